// Round 22
// baseline (76.642 us; speedup 1.0000x reference)
//
#include <hip/hip_runtime.h>
#include <cstdint>

#define N_WIRES 14
#define N_OPS   50
#define NSTATE  (1 << N_WIRES)   // 16384
#define BSZ     256
#define BLOCK   1024
#define LATENT  8
#define NCLMAX  50

// ================= compile-time numpy RNG + schedule (verified round-13/14) =================
namespace cg {
typedef unsigned __int128 u128;
struct PCG { u128 state; u128 inc; bool has32; uint32_t buf32; };

constexpr u128 pcg_mult() {
  return (((u128)2549297995355413924ULL) << 64) | 4865540595714422341ULL;
}
constexpr uint64_t n64(PCG &s) {
  s.state = s.state * pcg_mult() + s.inc;
  uint64_t x = (uint64_t)(s.state >> 64) ^ (uint64_t)s.state;
  unsigned r = (unsigned)(s.state >> 122);
  return (x >> (r & 63)) | (x << ((64 - r) & 63));
}
constexpr uint32_t n32(PCG &s) {
  if (s.has32) { s.has32 = false; return s.buf32; }
  uint64_t n = n64(s);
  s.has32 = true; s.buf32 = (uint32_t)(n >> 32);
  return (uint32_t)n;
}
constexpr uint32_t hashmix(uint32_t v, uint32_t &hc) {
  v ^= hc; hc *= 0x931e8875u; v *= hc; v ^= v >> 16; return v;
}
constexpr uint32_t mixf(uint32_t x, uint32_t y) {
  uint32_t r = x * 0xca01f9ddu - y * 0x4973f715u;   // multiply-SUBTRACT (verified)
  r ^= r >> 16; return r;
}
constexpr PCG seedseq(uint32_t entropy) {
  uint32_t pool[4] = {0, 0, 0, 0};
  uint32_t hc = 0x43b0d7e5u;
  pool[0] = hashmix(entropy, hc);
  for (int i = 1; i < 4; i++) pool[i] = hashmix(0u, hc);
  for (int s = 0; s < 4; s++)
    for (int d = 0; d < 4; d++)
      if (s != d) pool[d] = mixf(pool[d], hashmix(pool[s], hc));
  uint32_t w[8] = {};
  uint32_t hb = 0x8b51f9ddu;
  for (int i = 0; i < 8; i++) {
    uint32_t dv = pool[i & 3];
    dv ^= hb; hb *= 0x58f38dedu; dv *= hb; dv ^= dv >> 16; w[i] = dv;
  }
  uint64_t v0 = (uint64_t)w[0] | ((uint64_t)w[1] << 32);
  uint64_t v1 = (uint64_t)w[2] | ((uint64_t)w[3] << 32);
  uint64_t v2 = (uint64_t)w[4] | ((uint64_t)w[5] << 32);
  uint64_t v3 = (uint64_t)w[6] | ((uint64_t)w[7] << 32);
  PCG r{};
  u128 initstate = ((u128)v0 << 64) | v1;
  u128 initseq   = ((u128)v2 << 64) | v3;
  r.inc = (initseq << 1) | 1;
  r.state = 0;
  r.state = r.state * pcg_mult() + r.inc;
  r.state += initstate;
  r.state = r.state * pcg_mult() + r.inc;
  r.has32 = false; r.buf32 = 0;
  return r;
}
constexpr uint32_t lem32(PCG &r, uint32_t rmax) {
  uint32_t ex = rmax + 1u;
  uint64_t m = (uint64_t)n32(r) * ex;
  uint32_t lo = (uint32_t)m;
  if (lo < ex) {
    uint32_t t = (0xFFFFFFFFu - rmax) % ex;
    while (lo < t) { m = (uint64_t)n32(r) * ex; lo = (uint32_t)m; }
  }
  return (uint32_t)(m >> 32);
}

struct SchedC {
  int ncl;
  int cpos[NCLMAX * 3];
  int cng[NCLMAX];
  int cgoff[NCLMAX];
  int gpk[N_OPS];     // type | A<<2 | mode<<6 | lt<<7 | gidx<<9
};

// Slot-claiming rules: RX/RY claim their wire; CRX claims TARGET only (control is
// predication-only); RZ claims nothing (diagonal). Free wires are evaluated from bi.
constexpr SchedC make_sched() {
  int gt[N_OPS] = {}, g0[N_OPS] = {}, g1[N_OPS] = {};
  {
    PCG r = seedseq(1234u);
    for (int i = 0; i < N_OPS; i++) gt[i] = (int)lem32(r, 3);
    for (int i = 0; i < N_OPS; i++) {
      if (gt[i] < 3) { g0[i] = (int)lem32(r, 13); g1[i] = -1; continue; }
      uint32_t a = lem32(r, 12);
      uint32_t v = lem32(r, 13);
      uint32_t b = (v == a) ? 13u : v;
      uint32_t j = lem32(r, 1);
      if (j == 0) { uint32_t t = a; a = b; b = t; }
      g0[i] = (int)a; g1[i] = (int)b;
    }
  }
  SchedC S{};
  bool done[N_OPS] = {};
  int nsched = 0, ncl = 0, gcount = 0;
  while (nsched < N_OPS) {
    int posv[3] = {}, posn = 0;
    int clg[N_OPS] = {}, ncg = 0;
    bool progress = true;
    while (progress) {
      progress = false;
      for (int i = 0; i < N_OPS; i++) {
        if (done[i]) continue;
        bool avail = true;                 // frontier on FULL wire sets (ordering-safe)
        for (int j = 0; j < i && avail; j++) {
          if (done[j]) continue;
          if (g0[j] == g0[i] || (g1[i] >= 0 && g0[j] == g1[i])) avail = false;
          else if (g1[j] >= 0 && (g1[j] == g0[i] || (g1[i] >= 0 && g1[j] == g1[i]))) avail = false;
        }
        if (!avail) continue;
        // slot wire needed: RX/RY -> wire; CRX -> target; RZ -> none
        int sw = -1;
        if (gt[i] == 0 || gt[i] == 1) sw = 13 - g0[i];
        else if (gt[i] == 3) sw = 13 - g1[i];
        int need = 0;
        if (sw >= 0) {
          bool h = false;
          for (int k = 0; k < posn; k++) if (posv[k] == sw) h = true;
          if (!h) need = 1;
        }
        if (posn + need > 3) continue;
        if (need) posv[posn++] = sw;
        clg[ncg++] = i;
        done[i] = true; nsched++; progress = true;
      }
    }
    for (int p = 0; posn < 3 && p < 14; p++) {
      bool used = false;
      for (int k = 0; k < posn; k++) if (posv[k] == p) used = true;
      if (!used) posv[posn++] = p;
    }
    for (int a = 0; a < 2; a++)
      for (int b2 = a + 1; b2 < 3; b2++)
        if (posv[b2] < posv[a]) { int t = posv[a]; posv[a] = posv[b2]; posv[b2] = t; }
    for (int k = 0; k < 3; k++) S.cpos[ncl * 3 + k] = posv[k];
    S.cng[ncl] = ncg;
    S.cgoff[ncl] = gcount;
    for (int e = 0; e < ncg; e++) {
      int i = clg[e], t = gt[i];
      int A = 0, mode = 0, lt = 0;
      if (t <= 1) {
        int p = 13 - g0[i];
        for (int k = 0; k < 3; k++) if (posv[k] == p) A = k;
      } else if (t == 2) {
        int p = 13 - g0[i], s = -1;
        for (int k = 0; k < 3; k++) if (posv[k] == p) s = k;
        if (s >= 0) { A = s; mode = 0; } else { A = p; mode = 1; }
      } else {
        int pt = 13 - g1[i];
        for (int k = 0; k < 3; k++) if (posv[k] == pt) lt = k;
        int p = 13 - g0[i], s = -1;
        for (int k = 0; k < 3; k++) if (posv[k] == p) s = k;
        if (s >= 0) { A = s; mode = 0; } else { A = p; mode = 1; }
      }
      S.gpk[gcount++] = t | (A << 2) | (mode << 6) | (lt << 7) | (i << 9);
    }
    ncl++;
  }
  S.ncl = ncl;
  return S;
}

constexpr SchedC SC = make_sched();

// XOR nibble-fold swizzle on float2-index: conflict-free for all pow2 lane strides.
constexpr int swzc(int i) { return i ^ (((i >> 4) ^ (i >> 8) ^ (i >> 12)) & 15); }
} // namespace cg

__device__ __forceinline__ int swzd(int i) {
  return i ^ (((i >> 4) ^ (i >> 8) ^ (i >> 12)) & 15);
}

// ================= device: fully unrolled circuit =================
#define RXP(I0, I1) { float r0 = Ar[I0], q0_ = Ai[I0], r1 = Ar[I1], q1_ = Ai[I1]; \
  Ar[I0] = cc * r0 + ss * q1_; Ai[I0] = cc * q0_ - ss * r1; \
  Ar[I1] = cc * r1 + ss * q0_; Ai[I1] = cc * q1_ - ss * r0; }
#define RYP(I0, I1) { float r0 = Ar[I0], q0_ = Ai[I0], r1 = Ar[I1], q1_ = Ai[I1]; \
  Ar[I0] = cc * r0 - ss * r1; Ai[I0] = cc * q0_ - ss * q1_; \
  Ar[I1] = ss * r0 + cc * r1; Ai[I1] = ss * q0_ + cc * q1_; }
#define RZP(I0, I1) { float r0 = Ar[I0], q0_ = Ai[I0], r1 = Ar[I1], q1_ = Ai[I1]; \
  Ar[I0] = cc * r0 + ss * q0_; Ai[I0] = cc * q0_ - ss * r0; \
  Ar[I1] = cc * r1 - ss * q1_; Ai[I1] = cc * q1_ + ss * r1; }

template<int PK>
__device__ __forceinline__ void one_gate(float Ar[8], float Ai[8], const float2 *coef, int bi) {
  constexpr int t = PK & 3, A = (PK >> 2) & 15, mode = (PK >> 6) & 1,
                lt = (PK >> 7) & 3, gi = PK >> 9;
  const float2 cs = coef[gi];
  const float cc = cs.x, ss = cs.y;
  if constexpr (t == 0) {
    if constexpr (A == 0)      { RXP(0,1) RXP(2,3) RXP(4,5) RXP(6,7) }
    else if constexpr (A == 1) { RXP(0,2) RXP(1,3) RXP(4,6) RXP(5,7) }
    else                       { RXP(0,4) RXP(1,5) RXP(2,6) RXP(3,7) }
  } else if constexpr (t == 1) {
    if constexpr (A == 0)      { RYP(0,1) RYP(2,3) RYP(4,5) RYP(6,7) }
    else if constexpr (A == 1) { RYP(0,2) RYP(1,3) RYP(4,6) RYP(5,7) }
    else                       { RYP(0,4) RYP(1,5) RYP(2,6) RYP(3,7) }
  } else if constexpr (t == 2) {
    if constexpr (mode == 0) {
      if constexpr (A == 0)      { RZP(0,1) RZP(2,3) RZP(4,5) RZP(6,7) }
      else if constexpr (A == 1) { RZP(0,2) RZP(1,3) RZP(4,6) RZP(5,7) }
      else                       { RZP(0,4) RZP(1,5) RZP(2,6) RZP(3,7) }
    } else {
      // free-wire RZ: wire bit uniform across the 8 amps -> uniform phase
      const float sb_ = ((bi >> A) & 1) ? ss : -ss;
      #pragma unroll
      for (int j = 0; j < 8; j++) {
        float r0 = Ar[j], q0_ = Ai[j];
        Ar[j] = cc * r0 - sb_ * q0_;
        Ai[j] = cc * q0_ + sb_ * r0;
      }
    }
  } else {
    if constexpr (mode == 0) {
      constexpr int cse = A * 3 + lt;     // control slot A, target slot lt
      if constexpr (cse == 1)      { RXP(1,3) RXP(5,7) }
      else if constexpr (cse == 2) { RXP(1,5) RXP(3,7) }
      else if constexpr (cse == 3) { RXP(2,3) RXP(6,7) }
      else if constexpr (cse == 5) { RXP(2,6) RXP(3,7) }
      else if constexpr (cse == 6) { RXP(4,5) RXP(6,7) }
      else                         { RXP(4,6) RXP(5,7) }
    } else {
      // free-wire control: predicate via effective coefficients (identity when 0)
      const int bc = (bi >> A) & 1;
      const float cce = bc ? cc : 1.0f;
      const float sse = bc ? ss : 0.0f;
      {
        const float cc = cce, ss = sse;
        if constexpr (lt == 0)      { RXP(0,1) RXP(2,3) RXP(4,5) RXP(6,7) }
        else if constexpr (lt == 1) { RXP(0,2) RXP(1,3) RXP(4,6) RXP(5,7) }
        else                        { RXP(0,4) RXP(1,5) RXP(2,6) RXP(3,7) }
      }
    }
  }
}

template<int GOFF, int NG, int E>
__device__ __forceinline__ void gates_rec(float Ar[8], float Ai[8], const float2 *coef, int bi) {
  if constexpr (E < NG) {
    one_gate<cg::SC.gpk[GOFF + E]>(Ar, Ai, coef, bi);
    gates_rec<GOFF, NG, E + 1>(Ar, Ai, coef, bi);
  }
}

template<int C>
__device__ __forceinline__ void do_cluster(float2 *st, const float2 *coef, int tid,
                                           float (&pr)[LATENT]) {
  constexpr int q0 = cg::SC.cpos[3 * C], q1 = cg::SC.cpos[3 * C + 1], q2 = cg::SC.cpos[3 * C + 2];
  constexpr int ng = cg::SC.cng[C], goff = cg::SC.cgoff[C];
  constexpr int m0 = 1 << q0, m1 = 1 << q1, m2 = 1 << q2;
  constexpr bool LAST = (C == cg::SC.ncl - 1);
  constexpr int s1 = cg::swzc(m0),           s2 = cg::swzc(m1);
  constexpr int s3 = cg::swzc(m0 | m1),      s4 = cg::swzc(m2);
  constexpr int s5 = cg::swzc(m0 | m2),      s6 = cg::swzc(m1 | m2);
  constexpr int s7 = cg::swzc(m0 | m1 | m2);

  #pragma unroll 1                    // two 8-amp groups SEQUENTIAL (register cap)
  for (int grp = 0; grp < 2; ++grp) {
    int bi = tid + (grp << 10);
    bi = ((bi >> q0) << (q0 + 1)) | (bi & (m0 - 1));
    bi = ((bi >> q1) << (q1 + 1)) | (bi & (m1 - 1));
    bi = ((bi >> q2) << (q2 + 1)) | (bi & (m2 - 1));
    const int sb = swzd(bi);

    float Ar[8], Ai[8];
    { float2 v = st[sb];      Ar[0] = v.x; Ai[0] = v.y; }
    { float2 v = st[sb ^ s1]; Ar[1] = v.x; Ai[1] = v.y; }
    { float2 v = st[sb ^ s2]; Ar[2] = v.x; Ai[2] = v.y; }
    { float2 v = st[sb ^ s3]; Ar[3] = v.x; Ai[3] = v.y; }
    { float2 v = st[sb ^ s4]; Ar[4] = v.x; Ai[4] = v.y; }
    { float2 v = st[sb ^ s5]; Ar[5] = v.x; Ai[5] = v.y; }
    { float2 v = st[sb ^ s6]; Ar[6] = v.x; Ai[6] = v.y; }
    { float2 v = st[sb ^ s7]; Ar[7] = v.x; Ai[7] = v.y; }

    gates_rec<goff, ng, 0>(Ar, Ai, coef, bi);

    if constexpr (!LAST) {
      st[sb]      = make_float2(Ar[0], Ai[0]);
      st[sb ^ s1] = make_float2(Ar[1], Ai[1]);
      st[sb ^ s2] = make_float2(Ar[2], Ai[2]);
      st[sb ^ s3] = make_float2(Ar[3], Ai[3]);
      st[sb ^ s4] = make_float2(Ar[4], Ai[4]);
      st[sb ^ s5] = make_float2(Ar[5], Ai[5]);
      st[sb ^ s6] = make_float2(Ar[6], Ai[6]);
      st[sb ^ s7] = make_float2(Ar[7], Ai[7]);
    } else {
      #pragma unroll
      for (int j = 0; j < 8; j++) {
        float p2 = Ar[j] * Ar[j] + Ai[j] * Ai[j];
        int idx = bi | ((j & 1) ? m0 : 0) | ((j & 2) ? m1 : 0) | ((j & 4) ? m2 : 0);
        #pragma unroll
        for (int w = 0; w < LATENT; w++)
          pr[w] += ((idx >> (13 - w)) & 1) ? -p2 : p2;
      }
    }
  }
  if constexpr (!LAST) __syncthreads();
}

template<int C>
__device__ __forceinline__ void clusters_rec(float2 *st, const float2 *coef, int tid,
                                             float (&pr)[LATENT]) {
  if constexpr (C < cg::SC.ncl) {
    do_cluster<C>(st, coef, tid, pr);
    clusters_rec<C + 1>(st, coef, tid, pr);
  }
}

__global__ __launch_bounds__(BLOCK) void qae_k(
    const float* __restrict__ x, const float* __restrict__ rlp,
    float* __restrict__ out)
{
  __shared__ float2 st[NSTATE];                    // swizzled layout, no padding
  __shared__ float encc[N_WIRES], encs[N_WIRES];
  __shared__ float2 coef[N_OPS];
  const int b = blockIdx.x, tid = threadIdx.x;

  if (tid < N_WIRES) {
    float a = 0.5f * x[b * N_WIRES + tid];
    encc[tid] = cosf(a); encs[tid] = sinf(a);
  } else if (tid >= 64 && tid < 64 + N_OPS) {
    int g = tid - 64;
    float a = 0.5f * rlp[g];
    coef[g] = make_float2(cosf(a), sinf(a));
  }
  __syncthreads();

  // init sweep: product state (14 encoding RX gates fused); swizzled store
  #pragma unroll 1
  for (int k = tid; k < NSTATE; k += BLOCK) {
    float r = 1.0f;
    #pragma unroll
    for (int p = 0; p < N_WIRES; p++)
      r *= ((k >> p) & 1) ? encs[13 - p] : encc[13 - p];
    int pc = __popc((unsigned)k) & 3;
    st[swzd(k)] = make_float2((pc == 0) ? r : ((pc == 2) ? -r : 0.0f),
                              (pc == 1) ? -r : ((pc == 3) ? r : 0.0f));
  }
  __syncthreads();

  float pr[LATENT];
  #pragma unroll
  for (int w = 0; w < LATENT; w++) pr[w] = 0.0f;

  clusters_rec<0>(st, coef, tid, pr);              // the whole circuit, fully unrolled

  #pragma unroll
  for (int w = 0; w < LATENT; w++) {
    float v = pr[w];
    #pragma unroll
    for (int off = 32; off >= 1; off >>= 1) v += __shfl_down(v, off, 64);
    pr[w] = v;
  }
  __syncthreads();                                 // reuse st as reduction scratch
  float* red = (float*)st;
  const int wave = tid >> 6, lane = tid & 63;
  if (lane == 0) {
    #pragma unroll
    for (int w = 0; w < LATENT; w++) red[wave * LATENT + w] = pr[w];
  }
  __syncthreads();
  if (tid < LATENT) {
    float v = 0.0f;
    #pragma unroll
    for (int wv = 0; wv < BLOCK / 64; wv++) v += red[wv * LATENT + tid];
    out[b * LATENT + tid] = v;
  }
}

extern "C" void kernel_launch(void* const* d_in, const int* in_sizes, int n_in,
                              void* d_out, int out_size, void* d_ws, size_t ws_size,
                              hipStream_t stream) {
  const float *x   = (const float*)d_in[0];   // [256*14] f32
  const float *rlp = (const float*)d_in[1];   // [50] f32
  float *out = (float*)d_out;                 // [256*8] f32

  qae_k<<<dim3(BSZ), dim3(BLOCK), 0, stream>>>(x, rlp, out);
}

// Round 23
// 42.468 us; speedup vs baseline: 1.8047x; 1.8047x over previous
//
#include <hip/hip_runtime.h>
#include <cstdint>

#define N_WIRES 14
#define N_OPS   50
#define NSTATE  (1 << N_WIRES)   // 16384
#define BSZ     256
#define BLOCK   1024
#define LATENT  8
#define NCLMAX  50

// ================= compile-time numpy RNG + schedule (verified round-13/14) =================
namespace cg {
typedef unsigned __int128 u128;
struct PCG { u128 state; u128 inc; bool has32; uint32_t buf32; };

constexpr u128 pcg_mult() {
  return (((u128)2549297995355413924ULL) << 64) | 4865540595714422341ULL;
}
constexpr uint64_t n64(PCG &s) {
  s.state = s.state * pcg_mult() + s.inc;
  uint64_t x = (uint64_t)(s.state >> 64) ^ (uint64_t)s.state;
  unsigned r = (unsigned)(s.state >> 122);
  return (x >> (r & 63)) | (x << ((64 - r) & 63));
}
constexpr uint32_t n32(PCG &s) {
  if (s.has32) { s.has32 = false; return s.buf32; }
  uint64_t n = n64(s);
  s.has32 = true; s.buf32 = (uint32_t)(n >> 32);
  return (uint32_t)n;
}
constexpr uint32_t hashmix(uint32_t v, uint32_t &hc) {
  v ^= hc; hc *= 0x931e8875u; v *= hc; v ^= v >> 16; return v;
}
constexpr uint32_t mixf(uint32_t x, uint32_t y) {
  uint32_t r = x * 0xca01f9ddu - y * 0x4973f715u;   // multiply-SUBTRACT (verified)
  r ^= r >> 16; return r;
}
constexpr PCG seedseq(uint32_t entropy) {
  uint32_t pool[4] = {0, 0, 0, 0};
  uint32_t hc = 0x43b0d7e5u;
  pool[0] = hashmix(entropy, hc);
  for (int i = 1; i < 4; i++) pool[i] = hashmix(0u, hc);
  for (int s = 0; s < 4; s++)
    for (int d = 0; d < 4; d++)
      if (s != d) pool[d] = mixf(pool[d], hashmix(pool[s], hc));
  uint32_t w[8] = {};
  uint32_t hb = 0x8b51f9ddu;
  for (int i = 0; i < 8; i++) {
    uint32_t dv = pool[i & 3];
    dv ^= hb; hb *= 0x58f38dedu; dv *= hb; dv ^= dv >> 16; w[i] = dv;
  }
  uint64_t v0 = (uint64_t)w[0] | ((uint64_t)w[1] << 32);
  uint64_t v1 = (uint64_t)w[2] | ((uint64_t)w[3] << 32);
  uint64_t v2 = (uint64_t)w[4] | ((uint64_t)w[5] << 32);
  uint64_t v3 = (uint64_t)w[6] | ((uint64_t)w[7] << 32);
  PCG r{};
  u128 initstate = ((u128)v0 << 64) | v1;
  u128 initseq   = ((u128)v2 << 64) | v3;
  r.inc = (initseq << 1) | 1;
  r.state = 0;
  r.state = r.state * pcg_mult() + r.inc;
  r.state += initstate;
  r.state = r.state * pcg_mult() + r.inc;
  r.has32 = false; r.buf32 = 0;
  return r;
}
constexpr uint32_t lem32(PCG &r, uint32_t rmax) {
  uint32_t ex = rmax + 1u;
  uint64_t m = (uint64_t)n32(r) * ex;
  uint32_t lo = (uint32_t)m;
  if (lo < ex) {
    uint32_t t = (0xFFFFFFFFu - rmax) % ex;
    while (lo < t) { m = (uint64_t)n32(r) * ex; lo = (uint32_t)m; }
  }
  return (uint32_t)(m >> 32);
}

struct SchedC {
  int ncl;
  int cpos[NCLMAX * 3];
  int cng[NCLMAX];
  int cgoff[NCLMAX];
  int gpk[N_OPS];     // type | la<<2 | lt<<4 | gidx<<6
};

constexpr SchedC make_sched() {
  // --- gatespec (winner mapping m=1, round-14 decode) ---
  int gt[N_OPS] = {}, g0[N_OPS] = {}, g1[N_OPS] = {};
  {
    PCG r = seedseq(1234u);
    for (int i = 0; i < N_OPS; i++) gt[i] = (int)lem32(r, 3);
    for (int i = 0; i < N_OPS; i++) {
      if (gt[i] < 3) { g0[i] = (int)lem32(r, 13); g1[i] = -1; continue; }
      uint32_t a = lem32(r, 12);
      uint32_t v = lem32(r, 13);
      uint32_t b = (v == a) ? 13u : v;
      uint32_t j = lem32(r, 1);
      if (j == 0) { uint32_t t = a; a = b; b = t; }
      g0[i] = (int)a; g1[i] = (int)b;
    }
  }
  // --- 3-wire frontier clustering (identical to verified r18 host code) ---
  SchedC S{};
  bool done[N_OPS] = {};
  int nsched = 0, ncl = 0, gcount = 0;
  while (nsched < N_OPS) {
    int posv[3] = {}, posn = 0;
    int clg[N_OPS] = {}, ncg = 0;
    bool progress = true;
    while (progress) {
      progress = false;
      for (int i = 0; i < N_OPS; i++) {
        if (done[i]) continue;
        bool avail = true;
        for (int j = 0; j < i && avail; j++) {
          if (done[j]) continue;
          if (g0[j] == g0[i] || (g1[i] >= 0 && g0[j] == g1[i])) avail = false;
          else if (g1[j] >= 0 && (g1[j] == g0[i] || (g1[i] >= 0 && g1[j] == g1[i]))) avail = false;
        }
        if (!avail) continue;
        int p0 = 13 - g0[i];
        int p1 = (g1[i] >= 0) ? (13 - g1[i]) : -1;
        bool h0 = false, h1 = (p1 < 0);
        for (int k = 0; k < posn; k++) {
          if (posv[k] == p0) h0 = true;
          if (p1 >= 0 && posv[k] == p1) h1 = true;
        }
        int need = (h0 ? 0 : 1) + ((p1 >= 0 && !h1) ? 1 : 0);
        if (posn + need > 3) continue;
        if (!h0) posv[posn++] = p0;
        if (p1 >= 0 && !h1) posv[posn++] = p1;
        clg[ncg++] = i;
        done[i] = true; nsched++; progress = true;
      }
    }
    for (int p = 0; posn < 3 && p < 14; p++) {
      bool used = false;
      for (int k = 0; k < posn; k++) if (posv[k] == p) used = true;
      if (!used) posv[posn++] = p;
    }
    for (int a = 0; a < 2; a++)
      for (int b2 = a + 1; b2 < 3; b2++)
        if (posv[b2] < posv[a]) { int t = posv[a]; posv[a] = posv[b2]; posv[b2] = t; }
    for (int k = 0; k < 3; k++) S.cpos[ncl * 3 + k] = posv[k];
    S.cng[ncl] = ncg;
    S.cgoff[ncl] = gcount;
    for (int e = 0; e < ncg; e++) {
      int i = clg[e];
      int pa = 13 - g0[i], la = 0;
      for (int k = 0; k < 3; k++) if (posv[k] == pa) la = k;
      int lt = 0;
      if (g1[i] >= 0) {
        int pt = 13 - g1[i];
        for (int k = 0; k < 3; k++) if (posv[k] == pt) lt = k;
      }
      S.gpk[gcount++] = gt[i] | (la << 2) | (lt << 4) | (i << 6);
    }
    ncl++;
  }
  S.ncl = ncl;
  return S;
}

constexpr SchedC SC = make_sched();

// XOR nibble-fold swizzle on float2-index: conflict-free for all pow2 lane strides.
// XOR-linear: SWZ(a^b) = SWZ(a)^SWZ(b); identity for i<16.
constexpr int swzc(int i) { return i ^ (((i >> 4) ^ (i >> 8) ^ (i >> 12)) & 15); }
} // namespace cg

__device__ __forceinline__ int swzd(int i) {
  return i ^ (((i >> 4) ^ (i >> 8) ^ (i >> 12)) & 15);
}

// ================= device: fully unrolled circuit =================
#define RXP(I0, I1) { float r0 = Ar[I0], q0_ = Ai[I0], r1 = Ar[I1], q1_ = Ai[I1]; \
  Ar[I0] = cc * r0 + ss * q1_; Ai[I0] = cc * q0_ - ss * r1; \
  Ar[I1] = cc * r1 + ss * q0_; Ai[I1] = cc * q1_ - ss * r0; }
#define RYP(I0, I1) { float r0 = Ar[I0], q0_ = Ai[I0], r1 = Ar[I1], q1_ = Ai[I1]; \
  Ar[I0] = cc * r0 - ss * r1; Ai[I0] = cc * q0_ - ss * q1_; \
  Ar[I1] = ss * r0 + cc * r1; Ai[I1] = ss * q0_ + cc * q1_; }
#define RZP(I0, I1) { float r0 = Ar[I0], q0_ = Ai[I0], r1 = Ar[I1], q1_ = Ai[I1]; \
  Ar[I0] = cc * r0 + ss * q0_; Ai[I0] = cc * q0_ - ss * r0; \
  Ar[I1] = cc * r1 - ss * q1_; Ai[I1] = cc * q1_ + ss * r1; }

template<int PK>
__device__ __forceinline__ void one_gate(float Ar[8], float Ai[8], const float2 *coef) {
  constexpr int t = PK & 3, la = (PK >> 2) & 3, lt = (PK >> 4) & 3, gi = PK >> 6;
  const float2 cs = coef[gi];
  const float cc = cs.x, ss = cs.y;
  if constexpr (t == 0) {
    if constexpr (la == 0)      { RXP(0,1) RXP(2,3) RXP(4,5) RXP(6,7) }
    else if constexpr (la == 1) { RXP(0,2) RXP(1,3) RXP(4,6) RXP(5,7) }
    else                        { RXP(0,4) RXP(1,5) RXP(2,6) RXP(3,7) }
  } else if constexpr (t == 1) {
    if constexpr (la == 0)      { RYP(0,1) RYP(2,3) RYP(4,5) RYP(6,7) }
    else if constexpr (la == 1) { RYP(0,2) RYP(1,3) RYP(4,6) RYP(5,7) }
    else                        { RYP(0,4) RYP(1,5) RYP(2,6) RYP(3,7) }
  } else if constexpr (t == 2) {
    if constexpr (la == 0)      { RZP(0,1) RZP(2,3) RZP(4,5) RZP(6,7) }
    else if constexpr (la == 1) { RZP(0,2) RZP(1,3) RZP(4,6) RZP(5,7) }
    else                        { RZP(0,4) RZP(1,5) RZP(2,6) RZP(3,7) }
  } else {
    constexpr int cse = la * 3 + lt;
    if constexpr (cse == 1)      { RXP(1,3) RXP(5,7) }
    else if constexpr (cse == 2) { RXP(1,5) RXP(3,7) }
    else if constexpr (cse == 3) { RXP(2,3) RXP(6,7) }
    else if constexpr (cse == 5) { RXP(2,6) RXP(3,7) }
    else if constexpr (cse == 6) { RXP(4,5) RXP(6,7) }
    else                         { RXP(4,6) RXP(5,7) }
  }
}

template<int GOFF, int NG, int E>
__device__ __forceinline__ void gates_rec(float Ar[8], float Ai[8], const float2 *coef) {
  if constexpr (E < NG) {
    one_gate<cg::SC.gpk[GOFF + E]>(Ar, Ai, coef);
    gates_rec<GOFF, NG, E + 1>(Ar, Ai, coef);
  }
}

template<int C>
__device__ __forceinline__ void do_cluster(float2 *st, const float2 *coef, int tid,
                                           float (&pr)[LATENT]) {
  constexpr int q0 = cg::SC.cpos[3 * C], q1 = cg::SC.cpos[3 * C + 1], q2 = cg::SC.cpos[3 * C + 2];
  constexpr int ng = cg::SC.cng[C], goff = cg::SC.cgoff[C];
  constexpr int m0 = 1 << q0, m1 = 1 << q1, m2 = 1 << q2;
  constexpr bool LAST = (C == cg::SC.ncl - 1);
  // swizzled mask constants (SWZ is XOR-linear; bi and masks have disjoint bits)
  constexpr int s1 = cg::swzc(m0),           s2 = cg::swzc(m1);
  constexpr int s3 = cg::swzc(m0 | m1),      s4 = cg::swzc(m2);
  constexpr int s5 = cg::swzc(m0 | m2),      s6 = cg::swzc(m1 | m2);
  constexpr int s7 = cg::swzc(m0 | m1 | m2);

  #pragma unroll 1                    // two 8-amp groups SEQUENTIAL (register cap)
  for (int grp = 0; grp < 2; ++grp) {
    int bi = tid + (grp << 10);
    bi = ((bi >> q0) << (q0 + 1)) | (bi & (m0 - 1));
    bi = ((bi >> q1) << (q1 + 1)) | (bi & (m1 - 1));
    bi = ((bi >> q2) << (q2 + 1)) | (bi & (m2 - 1));
    const int sb = swzd(bi);

    float Ar[8], Ai[8];
    { float2 v = st[sb];      Ar[0] = v.x; Ai[0] = v.y; }
    { float2 v = st[sb ^ s1]; Ar[1] = v.x; Ai[1] = v.y; }
    { float2 v = st[sb ^ s2]; Ar[2] = v.x; Ai[2] = v.y; }
    { float2 v = st[sb ^ s3]; Ar[3] = v.x; Ai[3] = v.y; }
    { float2 v = st[sb ^ s4]; Ar[4] = v.x; Ai[4] = v.y; }
    { float2 v = st[sb ^ s5]; Ar[5] = v.x; Ai[5] = v.y; }
    { float2 v = st[sb ^ s6]; Ar[6] = v.x; Ai[6] = v.y; }
    { float2 v = st[sb ^ s7]; Ar[7] = v.x; Ai[7] = v.y; }

    gates_rec<goff, ng, 0>(Ar, Ai, coef);

    if constexpr (!LAST) {
      st[sb]      = make_float2(Ar[0], Ai[0]);
      st[sb ^ s1] = make_float2(Ar[1], Ai[1]);
      st[sb ^ s2] = make_float2(Ar[2], Ai[2]);
      st[sb ^ s3] = make_float2(Ar[3], Ai[3]);
      st[sb ^ s4] = make_float2(Ar[4], Ai[4]);
      st[sb ^ s5] = make_float2(Ar[5], Ai[5]);
      st[sb ^ s6] = make_float2(Ar[6], Ai[6]);
      st[sb ^ s7] = make_float2(Ar[7], Ai[7]);
    } else {
      #pragma unroll
      for (int j = 0; j < 8; j++) {
        float p2 = Ar[j] * Ar[j] + Ai[j] * Ai[j];
        int idx = bi | ((j & 1) ? m0 : 0) | ((j & 2) ? m1 : 0) | ((j & 4) ? m2 : 0);
        #pragma unroll
        for (int w = 0; w < LATENT; w++)
          pr[w] += ((idx >> (13 - w)) & 1) ? -p2 : p2;
      }
    }
  }
  if constexpr (!LAST) __syncthreads();
}

template<int C>
__device__ __forceinline__ void clusters_rec(float2 *st, const float2 *coef, int tid,
                                             float (&pr)[LATENT]) {
  if constexpr (C < cg::SC.ncl) {
    do_cluster<C>(st, coef, tid, pr);
    clusters_rec<C + 1>(st, coef, tid, pr);
  }
}

__global__ __launch_bounds__(BLOCK) void qae_k(
    const float* __restrict__ x, const float* __restrict__ rlp,
    float* __restrict__ out)
{
  __shared__ float2 st[NSTATE];                    // swizzled layout, no padding
  __shared__ float encc[N_WIRES], encs[N_WIRES];
  __shared__ float2 coef[N_OPS];
  const int b = blockIdx.x, tid = threadIdx.x;

  if (tid < N_WIRES) {
    float a = 0.5f * x[b * N_WIRES + tid];
    encc[tid] = cosf(a); encs[tid] = sinf(a);
  } else if (tid >= 64 && tid < 64 + N_OPS) {
    int g = tid - 64;
    float a = 0.5f * rlp[g];
    coef[g] = make_float2(cosf(a), sinf(a));
  }
  __syncthreads();

  // init sweep: product state (14 encoding RX gates fused); swizzled store
  #pragma unroll 1
  for (int k = tid; k < NSTATE; k += BLOCK) {
    float r = 1.0f;
    #pragma unroll
    for (int p = 0; p < N_WIRES; p++)
      r *= ((k >> p) & 1) ? encs[13 - p] : encc[13 - p];
    int pc = __popc((unsigned)k) & 3;
    st[swzd(k)] = make_float2((pc == 0) ? r : ((pc == 2) ? -r : 0.0f),
                              (pc == 1) ? -r : ((pc == 3) ? r : 0.0f));
  }
  __syncthreads();

  float pr[LATENT];
  #pragma unroll
  for (int w = 0; w < LATENT; w++) pr[w] = 0.0f;

  clusters_rec<0>(st, coef, tid, pr);              // the whole circuit, fully unrolled

  #pragma unroll
  for (int w = 0; w < LATENT; w++) {
    float v = pr[w];
    #pragma unroll
    for (int off = 32; off >= 1; off >>= 1) v += __shfl_down(v, off, 64);
    pr[w] = v;
  }
  __syncthreads();                                 // reuse st as reduction scratch
  float* red = (float*)st;
  const int wave = tid >> 6, lane = tid & 63;
  if (lane == 0) {
    #pragma unroll
    for (int w = 0; w < LATENT; w++) red[wave * LATENT + w] = pr[w];
  }
  __syncthreads();
  if (tid < LATENT) {
    float v = 0.0f;
    #pragma unroll
    for (int wv = 0; wv < BLOCK / 64; wv++) v += red[wv * LATENT + tid];
    out[b * LATENT + tid] = v;
  }
}

extern "C" void kernel_launch(void* const* d_in, const int* in_sizes, int n_in,
                              void* d_out, int out_size, void* d_ws, size_t ws_size,
                              hipStream_t stream) {
  const float *x   = (const float*)d_in[0];   // [256*14] f32
  const float *rlp = (const float*)d_in[1];   // [50] f32
  float *out = (float*)d_out;                 // [256*8] f32

  qae_k<<<dim3(BSZ), dim3(BLOCK), 0, stream>>>(x, rlp, out);
}